// Round 5
// baseline (34.488 us; speedup 1.0000x reference)
//
#include <hip/hip_runtime.h>

// BathtubReconstructor: per (b,y,x,t) coarse cell, solve
//   mean_k relu(h - z_k) == d_target   (16 fine topo values z_k per cell)
// analytically (exact water-filling), then write relu(h - z_k) to the fine
// output grid.
//
// R5: R4's lane mapping {tq(8) x fx(4) x cell(2)} -> each wave store
// instruction covers 1024 B fully contiguous (same as the 6.7 TB/s fill
// kernel's pattern), but with PLAIN float4 stores — R4 showed nontemporal
// stores regress (bypass L2 write-combining). Isolates mapping from NT.

__global__ __launch_bounds__(256) void bathtub_kernel(
    const float* __restrict__ u_coarse,   // (16, 64, 64, 32) fp32
    const float* __restrict__ topo,       // (256, 256) fp32
    float* __restrict__ out,              // (16, 256, 256, 32) fp32
    int nthreads)                         // 2,097,152
{
    const int tid = blockIdx.x * 256 + threadIdx.x;
    if (tid >= nthreads) return;

    // tid = ((cell)*4 + fx)*8 + tq ; cell = ((b*64 + y)*64 + x)
    const int tq   = tid & 7;            // t-quad: t = 4*tq .. 4*tq+3
    const int fx   = (tid >> 3) & 3;     // fine-x within coarse cell
    const int cell = tid >> 5;
    const int x    = cell & 63;
    const int y    = (cell >> 6) & 63;
    const int b    = cell >> 12;

    // z_k for k = fy*4 + fx  <=>  topo[y*4+fy][x*4+fx]   (L1/L2 cached, 256 KB)
    float z[16];
    const float* trow = topo + (y * 4) * 256 + x * 4;
#pragma unroll
    for (int fy = 0; fy < 4; ++fy) {
        const float4 v = *reinterpret_cast<const float4*>(trow + fy * 256);
        z[fy * 4 + 0] = v.x;
        z[fy * 4 + 1] = v.y;
        z[fy * 4 + 2] = v.z;
        z[fy * 4 + 3] = v.w;
    }

    // 4 depth targets for this (cell, t-quad)
    const float4 d4 = *reinterpret_cast<const float4*>(u_coarse + cell * 32 + tq * 4);
    float dd[4] = {d4.x, d4.y, d4.z, d4.w};

    // ---- sort a copy ascending (bitonic network, fully unrolled -> VGPRs) ----
    float s[16];
#pragma unroll
    for (int k = 0; k < 16; ++k) s[k] = z[k];

#pragma unroll
    for (int k = 2; k <= 16; k <<= 1) {
#pragma unroll
        for (int j = k >> 1; j > 0; j >>= 1) {
#pragma unroll
            for (int i = 0; i < 16; ++i) {
                const int ixj = i ^ j;
                if (ixj > i) {
                    const bool asc = ((i & k) == 0);
                    const float a = s[i], c = s[ixj];
                    const float lo = fminf(a, c), hi = fmaxf(a, c);
                    s[i]   = asc ? lo : hi;
                    s[ixj] = asc ? hi : lo;
                }
            }
        }
    }

    // ---- prefix sums: S[k] = s[0] + ... + s[k] ----
    float S[16];
    float run = 0.0f;
#pragma unroll
    for (int k = 0; k < 16; ++k) { run += s[k]; S[k] = run; }

    // ---- exact water level per t ----
    // Segment j (j submerged cells): h_j = (16*d + S_{j-1}) / j. h_j <= s[j]
    // holds iff j >= j*; pick smallest such j by branchless downward overwrite.
    float h[4];
#pragma unroll
    for (int i = 0; i < 4; ++i) {
        const float T16 = 16.0f * dd[i];
        float hv = (T16 + S[15]) * (1.0f / 16.0f);   // j = 16 fallback
#pragma unroll
        for (int j = 15; j >= 1; --j) {
            const float hj = (T16 + S[j - 1]) * (1.0f / (float)j);
            hv = (hj <= s[j]) ? hj : hv;
        }
        h[i] = hv;
    }

    // ---- emit: out[b][y*4+fy][x*4+fx][4*tq + 0..3] = relu(h - z[fy*4+fx]) ----
    // Per store instruction a wave covers 1024 B contiguous (tq,fx,cell in-lane).
    const int rowbase = ((b * 256 + y * 4) * 256 + (x * 4 + fx)) * 32 + tq * 4;
#pragma unroll
    for (int fy = 0; fy < 4; ++fy) {
        const float zz = z[fy * 4 + fx];
        float4 v;
        v.x = fmaxf(h[0] - zz, 0.0f);
        v.y = fmaxf(h[1] - zz, 0.0f);
        v.z = fmaxf(h[2] - zz, 0.0f);
        v.w = fmaxf(h[3] - zz, 0.0f);
        *reinterpret_cast<float4*>(out + rowbase + fy * (256 * 32)) = v;
    }
}

extern "C" void kernel_launch(void* const* d_in, const int* in_sizes, int n_in,
                              void* d_out, int out_size, void* d_ws, size_t ws_size,
                              hipStream_t stream) {
    const float* u_coarse = (const float*)d_in[0];  // (16,64,64,32) fp32
    const float* topo     = (const float*)d_in[1];  // (256,256) fp32
    float* out            = (float*)d_out;          // (16,256,256,32) fp32

    const int nthreads = in_sizes[0];               // 2,097,152
    const int blocks   = (nthreads + 255) / 256;
    bathtub_kernel<<<blocks, 256, 0, stream>>>(u_coarse, topo, out, nthreads);
}

// Round 6
// 27.476 us; speedup vs baseline: 1.2552x; 1.2552x over previous
//
#include <hip/hip_runtime.h>

// BathtubReconstructor: per (b,y,x,t) coarse cell, solve
//   mean_k relu(h - z_k) == d_target   (16 fine topo values z_k per cell)
// analytically (exact water-filling), then write relu(h - z_k) to the fine
// output grid.
//
// R6 = R2 (best known, 27.5 us) restored verbatim.
// Session evidence: R1 (scalar stores) 27.8; R2 (t-quad float4) 27.5;
// R4 (wave-contiguous remap + NT stores) 33.1; R5 (remap, plain) 34.5.
// => plateau at ~5.0-5.2 TB/s combined is insensitive to store micro-pattern;
// fill-like lane remaps regress. 137 MB mandatory traffic / 27.5 us = 79% of
// the float4-copy ceiling (6.3 TB/s) -- the structural floor is the 128 MiB
// fp32 output write stream.

__global__ __launch_bounds__(256) void bathtub_kernel(
    const float* __restrict__ u_coarse,   // (16, 64, 64, 32) fp32
    const float* __restrict__ topo,       // (256, 256) fp32
    float* __restrict__ out,              // (16, 256, 256, 32) fp32
    int nquads)                           // total/4
{
    const int tid = blockIdx.x * 256 + threadIdx.x;
    if (tid >= nquads) return;

    // tid = cell*8 + tq ; cell = ((b*64 + y)*64 + x)
    const int tq   = tid & 7;            // t-quad: t = 4*tq .. 4*tq+3
    const int cell = tid >> 3;
    const int x    = cell & 63;
    const int y    = (cell >> 6) & 63;
    const int b    = cell >> 12;

    // z_k for k = fy*4 + fx  <=>  topo[y*4+fy][x*4+fx]   (L1/L2 cached, 256 KB)
    float z[16];
    const float* trow = topo + (y * 4) * 256 + x * 4;
#pragma unroll
    for (int fy = 0; fy < 4; ++fy) {
        const float4 v = *reinterpret_cast<const float4*>(trow + fy * 256);
        z[fy * 4 + 0] = v.x;
        z[fy * 4 + 1] = v.y;
        z[fy * 4 + 2] = v.z;
        z[fy * 4 + 3] = v.w;
    }

    // 4 depth targets (contiguous in t -> one coalesced float4 load)
    const float4 d4 = *reinterpret_cast<const float4*>(u_coarse + tid * 4);
    float dd[4] = {d4.x, d4.y, d4.z, d4.w};

    // ---- sort a copy ascending (bitonic network, fully unrolled -> VGPRs) ----
    float s[16];
#pragma unroll
    for (int k = 0; k < 16; ++k) s[k] = z[k];

#pragma unroll
    for (int k = 2; k <= 16; k <<= 1) {
#pragma unroll
        for (int j = k >> 1; j > 0; j >>= 1) {
#pragma unroll
            for (int i = 0; i < 16; ++i) {
                const int ixj = i ^ j;
                if (ixj > i) {
                    const bool asc = ((i & k) == 0);
                    const float a = s[i], c = s[ixj];
                    const float lo = fminf(a, c), hi = fmaxf(a, c);
                    s[i]   = asc ? lo : hi;
                    s[ixj] = asc ? hi : lo;
                }
            }
        }
    }

    // ---- prefix sums: S[k] = s[0] + ... + s[k] ----
    float S[16];
    float run = 0.0f;
#pragma unroll
    for (int k = 0; k < 16; ++k) { run += s[k]; S[k] = run; }

    // ---- exact water level per t ----
    // Segment j (j submerged cells): h_j = (16*d + S_{j-1}) / j. h_j <= s[j]
    // holds iff j >= j*; pick smallest such j by branchless downward overwrite.
    float h[4];
#pragma unroll
    for (int i = 0; i < 4; ++i) {
        const float T16 = 16.0f * dd[i];
        float hv = (T16 + S[15]) * (1.0f / 16.0f);   // j = 16 fallback
#pragma unroll
        for (int j = 15; j >= 1; --j) {
            const float hj = (T16 + S[j - 1]) * (1.0f / (float)j);
            hv = (hj <= s[j]) ? hj : hv;
        }
        h[i] = hv;
    }

    // ---- emit: out[b][y*4+fy][x*4+fx][4*tq + 0..3] = relu(h - z_k) ----
    const int obase = ((b * 256 + y * 4) * 256 + x * 4) * 32 + tq * 4;
#pragma unroll
    for (int fy = 0; fy < 4; ++fy) {
#pragma unroll
        for (int fx = 0; fx < 4; ++fx) {
            const float zz = z[fy * 4 + fx];
            float4 v;
            v.x = fmaxf(h[0] - zz, 0.0f);
            v.y = fmaxf(h[1] - zz, 0.0f);
            v.z = fmaxf(h[2] - zz, 0.0f);
            v.w = fmaxf(h[3] - zz, 0.0f);
            *reinterpret_cast<float4*>(out + obase + (fy * 256 + fx) * 32) = v;
        }
    }
}

extern "C" void kernel_launch(void* const* d_in, const int* in_sizes, int n_in,
                              void* d_out, int out_size, void* d_ws, size_t ws_size,
                              hipStream_t stream) {
    const float* u_coarse = (const float*)d_in[0];  // (16,64,64,32) fp32
    const float* topo     = (const float*)d_in[1];  // (256,256) fp32
    float* out            = (float*)d_out;          // (16,256,256,32) fp32

    const int nquads = in_sizes[0] / 4;             // 524,288 threads
    const int blocks = (nquads + 255) / 256;
    bathtub_kernel<<<blocks, 256, 0, stream>>>(u_coarse, topo, out, nquads);
}